// Round 2
// baseline (774.404 us; speedup 1.0000x reference)
//
#include <hip/hip_runtime.h>

// LogicVAE: graph-GRU VAE encoder. B=2048,N=32,V=10,H=256,Z=64.
// gm[b,n] = sigmoid(h@w_gate+b_gate)*(h@w_map) is a pure function of the FINAL
// hidden[b,n] (adj strictly upper-tri => rows >= v contribute 0), so compute it
// once per node when h_new is produced; per step only a sparse agg + 2 MFMA GEMMs.
// Dtype of float tensors (fp32 vs bf16 storage) is detected at runtime; both
// templated variants launch each call and self-select on a device flag.

#define BB 2048
#define NN 32
#define VV 10
#define HH 256
#define ZZ 64
#define BT 8      // batches per block
#define KC 8      // K chunks: 256/32
#define NT1 48    // 768/16 col tiles (w_hh)
#define NT2 32    // 512/16 col tiles (w_gate||w_map)
#define WHH_ELEMS (NT1 * KC * 64 * 8)            // 196608 ushorts
#define WGM_ELEMS (NT2 * KC * 64 * 8)            // 131072 ushorts
#define GM_BYTE_OFF ((WHH_ELEMS + WGM_ELEMS) * 2) // 655360 B
#define SLAB_ELEMS (BT * NN * HH)                 // 65536 ushorts
#define SLAB_BYTES (SLAB_ELEMS * 2)               // 131072 B

typedef __attribute__((ext_vector_type(8))) short frag8;   // 8 bf16 (4 VGPR)
typedef __attribute__((ext_vector_type(4))) float facc4;   // MFMA accum

__device__ __forceinline__ float bf2f(unsigned short u) {
    unsigned int x = ((unsigned int)u) << 16;
    return __builtin_bit_cast(float, x);
}
__device__ __forceinline__ unsigned short f2bf(float f) {
    unsigned int x = __builtin_bit_cast(unsigned int, f);
    x += 0x7FFFu + ((x >> 16) & 1u);
    return (unsigned short)(x >> 16);
}
__device__ __forceinline__ float sigm(float x) { return 1.0f / (1.0f + __expf(-x)); }
__device__ __forceinline__ float ldv(const float* p, size_t i) { return p[i]; }
__device__ __forceinline__ float ldv(const unsigned short* p, size_t i) { return bf2f(p[i]); }
__device__ __forceinline__ void stv(float* p, size_t i, float v) { p[i] = v; }
__device__ __forceinline__ void stv(unsigned short* p, size_t i, float v) { p[i] = f2bf(v); }

// flag=1 => buffers are fp32, flag=0 => bf16. Integer-only tests (fast-math safe).
__global__ void detect_dtype(const unsigned short* __restrict__ w, int* flag) {
    __shared__ int zc, bc;
    if (threadIdx.x == 0) { zc = 0; bc = 0; }
    __syncthreads();
    int z = 0, b = 0;
    for (int i = threadIdx.x; i < 2048; i += 256) {
        unsigned short lo = w[2 * i];            // fp32: low mantissa half / bf16: a value
        if (lo == 0) z++;                        // bf16-rounded fp32 storage => all zero
        unsigned e = (lo >> 7) & 0xFFu;          // bf16 exponent field
        if (e >= 0x86u) b++;                     // |x|>=128 or NaN: impossible for N(0,.05) bf16
    }
    atomicAdd(&zc, z); atomicAdd(&bc, b);
    __syncthreads();
    if (threadIdx.x == 0) *flag = (bc > 0 || zc > 512) ? 1 : 0;
}

// Repack w_hh (256x768) and w_gate||w_map (256x512) into bf16 MFMA B-fragment
// order: frag f=jt*KC+kc; elem[(f*64+lane)*8+j] = W[kc*32+(lane>>4)*8+j][jt*16+(lane&15)]
template <typename T>
__global__ void repack_weights(const T* __restrict__ w_hh,
                               const T* __restrict__ w_gate,
                               const T* __restrict__ w_map,
                               unsigned short* __restrict__ whh_p,
                               unsigned short* __restrict__ wgm_p,
                               const int* __restrict__ flag, int want) {
    if (*flag != want) return;
    int t = blockIdx.x * blockDim.x + threadIdx.x;
    int lane = t & 63;
    int frag = t >> 6;                  // 0..639
    int kbase = (lane >> 4) * 8;
    if (frag < NT1 * KC) {
        int jt = frag / KC, kc = frag % KC;
        int col = jt * 16 + (lane & 15);
        unsigned short* dst = whh_p + ((size_t)frag * 64 + lane) * 8;
        #pragma unroll
        for (int j = 0; j < 8; ++j)
            dst[j] = f2bf(ldv(w_hh, (size_t)(kc * 32 + kbase + j) * 768 + col));
    } else if (frag < (NT1 + NT2) * KC) {
        int f2 = frag - NT1 * KC;
        int jt = f2 / KC, kc = f2 % KC;
        int col = jt * 16 + (lane & 15);
        unsigned short* dst = wgm_p + ((size_t)f2 * 64 + lane) * 8;
        #pragma unroll
        for (int j = 0; j < 8; ++j) {
            int k = kc * 32 + kbase + j;
            dst[j] = f2bf((col < HH) ? ldv(w_gate, (size_t)k * HH + col)
                                     : ldv(w_map, (size_t)k * HH + (col - HH)));
        }
    }
}

template <typename T>
__global__ __launch_bounds__(512, 2) void vae_main(
    const T* __restrict__ adj,
    const int* __restrict__ ntypes,
    const T* __restrict__ w_ih,
    const T* __restrict__ b_ih,
    const T* __restrict__ b_hh,
    const T* __restrict__ b_gate,
    const T* __restrict__ w_mu,
    const T* __restrict__ b_mu,
    const T* __restrict__ w_std,
    const T* __restrict__ b_std,
    const unsigned short* __restrict__ whh_p,
    const unsigned short* __restrict__ wgm_p,
    unsigned short* __restrict__ gm_base,
    T* __restrict__ out,
    int b_start,
    const int* __restrict__ flag, int want)
{
    if (*flag != want) return;

    __shared__ __align__(16) float agg[BT][HH];             // fp32 agg (8 KB)
    __shared__ __align__(16) float adjc[BT][NN];            // adj column (1 KB)
    __shared__ int ntv[BT];
    __shared__ __align__(16) unsigned short aggbf[16][264]; // MFMA A src (pad +8)
    __shared__ __align__(16) unsigned short hnew[16][264];  // MFMA A src (pad +8)

    const int tid  = threadIdx.x;
    const int lane = tid & 63;
    const int wv   = tid >> 6;          // 0..7
    const int b0   = b_start + blockIdx.x * BT;

    unsigned short* gms = gm_base + (size_t)blockIdx.x * SLAB_ELEMS;  // per-block slab

    const frag8* whh8 = (const frag8*)whh_p;
    const frag8* wgm8 = (const frag8*)wgm_p;

    // zero rows 8..15 of A-operand tiles (M=16, only 8 batches valid)
    for (int i = 8 * 264 + tid; i < 16 * 264; i += 512) {
        ((unsigned short*)aggbf)[i] = 0;
        ((unsigned short*)hnew)[i]  = 0;
    }

    for (int v = 0; v < NN; ++v) {
        // ---- A0: stage adj column + node types
        if (tid < BT * NN) {
            int bi = tid >> 5, n = tid & 31;
            adjc[bi][n] = ldv(adj, ((size_t)(b0 + bi) * NN + n) * NN + v);
        }
        if (tid < BT) ntv[tid] = ntypes[(b0 + tid) * NN + v];
        __syncthreads();

        // ---- A: agg[bi][:] = sum_{n<v} adj * gm[bi][n][:]  (wave wv owns bi=wv)
        {
            const int bi = wv;
            const int h4 = lane * 4;
            float a0 = 0.f, a1 = 0.f, a2 = 0.f, a3 = 0.f;
            for (int n = 0; n < v; ++n) {
                float w = adjc[bi][n];          // LDS broadcast -> wave-uniform branch
                if (w != 0.0f) {
                    ushort4 g = *(const ushort4*)(gms + (size_t)(bi * NN + n) * HH + h4);
                    a0 += w * bf2f(g.x); a1 += w * bf2f(g.y);
                    a2 += w * bf2f(g.z); a3 += w * bf2f(g.w);
                }
            }
            *(float4*)&agg[bi][h4] = make_float4(a0, a1, a2, a3);
            ushort4 ab; ab.x = f2bf(a0); ab.y = f2bf(a1); ab.z = f2bf(a2); ab.w = f2bf(a3);
            *(ushort4*)&aggbf[bi][h4] = ab;
        }
        __syncthreads();

        // ---- B: gh = agg @ w_hh (MFMA) fused with GRU elementwise -> hnew
        frag8 afrag[KC];
        #pragma unroll
        for (int kc = 0; kc < KC; ++kc)
            afrag[kc] = *(const frag8*)&aggbf[lane & 15][kc * 32 + (lane >> 4) * 8];

        #pragma unroll
        for (int tt = 0; tt < 2; ++tt) {
            const int t = 2 * wv + tt;                   // triplet: cols t, t+16, t+32
            facc4 aR = {0.f, 0.f, 0.f, 0.f};
            facc4 aZ = {0.f, 0.f, 0.f, 0.f};
            facc4 aN = {0.f, 0.f, 0.f, 0.f};
            const frag8* pR = whh8 + (size_t)(t     ) * KC * 64 + lane;
            const frag8* pZ = whh8 + (size_t)(t + 16) * KC * 64 + lane;
            const frag8* pN = whh8 + (size_t)(t + 32) * KC * 64 + lane;
            #pragma unroll
            for (int kc = 0; kc < KC; ++kc) {
                aR = __builtin_amdgcn_mfma_f32_16x16x32_bf16(afrag[kc], pR[kc * 64], aR, 0, 0, 0);
                aZ = __builtin_amdgcn_mfma_f32_16x16x32_bf16(afrag[kc], pZ[kc * 64], aZ, 0, 0, 0);
                aN = __builtin_amdgcn_mfma_f32_16x16x32_bf16(afrag[kc], pN[kc * 64], aN, 0, 0, 0);
            }
            const int col = t * 16 + (lane & 15);
            const int q = lane >> 4;                     // C row = 4q+i, valid q<2
            if (q < 2) {
                const float bir  = ldv(b_ih, col),          bhr = ldv(b_hh, col);
                const float biz  = ldv(b_ih, col + HH),     bhz = ldv(b_hh, col + HH);
                const float bin_ = ldv(b_ih, col + 2 * HH), bhn = ldv(b_hh, col + 2 * HH);
                #pragma unroll
                for (int i = 0; i < 4; ++i) {
                    const int bi = 4 * q + i;
                    const size_t ty = (size_t)ntv[bi] * 768;
                    const float r = sigm(ldv(w_ih, ty + col) + bir + aR[i] + bhr);
                    const float z = sigm(ldv(w_ih, ty + col + HH) + biz + aZ[i] + bhz);
                    const float n = tanhf(ldv(w_ih, ty + col + 2 * HH) + bin_ + r * (aN[i] + bhn));
                    const float h = (1.f - z) * n + z * agg[bi][col];
                    hnew[bi][col] = f2bf(h);
                }
            }
        }
        __syncthreads();

        // ---- D: gm_v = sigmoid(h@w_gate+b_gate) * (h@w_map) (MFMA), store row v
        frag8 hfrag[KC];
        #pragma unroll
        for (int kc = 0; kc < KC; ++kc)
            hfrag[kc] = *(const frag8*)&hnew[lane & 15][kc * 32 + (lane >> 4) * 8];

        #pragma unroll
        for (int tt = 0; tt < 2; ++tt) {
            const int t = 2 * wv + tt;                   // gate tile t, map tile t+16
            facc4 aG = {0.f, 0.f, 0.f, 0.f};
            facc4 aM = {0.f, 0.f, 0.f, 0.f};
            const frag8* pG = wgm8 + (size_t)(t     ) * KC * 64 + lane;
            const frag8* pM = wgm8 + (size_t)(t + 16) * KC * 64 + lane;
            #pragma unroll
            for (int kc = 0; kc < KC; ++kc) {
                aG = __builtin_amdgcn_mfma_f32_16x16x32_bf16(hfrag[kc], pG[kc * 64], aG, 0, 0, 0);
                aM = __builtin_amdgcn_mfma_f32_16x16x32_bf16(hfrag[kc], pM[kc * 64], aM, 0, 0, 0);
            }
            const int col = t * 16 + (lane & 15);        // 0..255
            const int q = lane >> 4;
            if (q < 2) {
                const float bg = ldv(b_gate, col);
                #pragma unroll
                for (int i = 0; i < 4; ++i) {
                    const int bi = 4 * q + i;
                    const float gv = sigm(aG[i] + bg) * aM[i];
                    gms[(size_t)(bi * NN + v) * HH + col] = f2bf(gv);
                }
            }
        }
        __syncthreads();   // hnew/gm consumed before next iteration overwrites
    }

    // ---- Epilogue: hg = h_new(v=31) (in hnew LDS); mu/sigma = hg@w_mu/std + b
    {
        const int bi = wv;       // 0..7
        const int z  = lane;     // 0..63
        float am = ldv(b_mu, z);
        float as = ldv(b_std, z);
        for (int h = 0; h < HH; ++h) {
            const float hv = bf2f(hnew[bi][h]);   // LDS broadcast
            am += hv * ldv(w_mu, (size_t)h * ZZ + z);
            as += hv * ldv(w_std, (size_t)h * ZZ + z);
        }
        stv(out, (size_t)(b0 + bi) * ZZ + z, am);
        stv(out, (size_t)BB * ZZ + (size_t)(b0 + bi) * ZZ + z, as);
    }
}

extern "C" void kernel_launch(void* const* d_in, const int* in_sizes, int n_in,
                              void* d_out, int out_size, void* d_ws, size_t ws_size,
                              hipStream_t stream)
{
    unsigned short* whh_p = (unsigned short*)d_ws;
    unsigned short* wgm_p = whh_p + WHH_ELEMS;
    unsigned short* gm_base = wgm_p + WGM_ELEMS;           // byte offset 655360

    // dtype flag lives in the last aligned 4 bytes of ws
    size_t flag_off = (ws_size >= 8) ? ((ws_size - 4) & ~(size_t)3) : 0;
    int* flag = (int*)((char*)d_ws + flag_off);

    // how many blocks' gm slabs fit between repacked weights and the flag
    long long avail = (long long)flag_off - (long long)GM_BYTE_OFF;
    int cb = (int)(avail / SLAB_BYTES);
    if (cb < 1) cb = 1;                                    // degenerate ws: best effort
    if (cb > BB / BT) cb = BB / BT;

    detect_dtype<<<dim3(1), 256, 0, stream>>>((const unsigned short*)d_in[2], flag);

    repack_weights<float><<<dim3(160), 256, 0, stream>>>(
        (const float*)d_in[3], (const float*)d_in[6], (const float*)d_in[8],
        whh_p, wgm_p, flag, 1);
    repack_weights<unsigned short><<<dim3(160), 256, 0, stream>>>(
        (const unsigned short*)d_in[3], (const unsigned short*)d_in[6],
        (const unsigned short*)d_in[8], whh_p, wgm_p, flag, 0);

    const int nblk = BB / BT;                              // 256
    for (int blk0 = 0; blk0 < nblk; blk0 += cb) {
        int g = nblk - blk0; if (g > cb) g = cb;
        vae_main<float><<<dim3(g), 512, 0, stream>>>(
            (const float*)d_in[0], (const int*)d_in[1], (const float*)d_in[2],
            (const float*)d_in[4], (const float*)d_in[5], (const float*)d_in[7],
            (const float*)d_in[9], (const float*)d_in[10], (const float*)d_in[11],
            (const float*)d_in[12],
            whh_p, wgm_p, gm_base, (float*)d_out, blk0 * BT, flag, 1);
        vae_main<unsigned short><<<dim3(g), 512, 0, stream>>>(
            (const unsigned short*)d_in[0], (const int*)d_in[1],
            (const unsigned short*)d_in[2], (const unsigned short*)d_in[4],
            (const unsigned short*)d_in[5], (const unsigned short*)d_in[7],
            (const unsigned short*)d_in[9], (const unsigned short*)d_in[10],
            (const unsigned short*)d_in[11], (const unsigned short*)d_in[12],
            whh_p, wgm_p, gm_base, (unsigned short*)d_out, blk0 * BT, flag, 0);
    }
}

// Round 4
// 580.488 us; speedup vs baseline: 1.3341x; 1.3341x over previous
//
#include <hip/hip_runtime.h>

// LogicVAE: graph-GRU VAE encoder. B=2048,N=32,V=10,H=256,Z=64.
// gm[b,n] = sigmoid(h@w_gate+b_gate)*(h@w_map) is a pure function of the FINAL
// hidden[b,n] (adj strictly upper-tri), so it's computed once per node.
// R4 = R3 with nontemporal builtin types fixed (clang ext_vector, not ushort4):
//  - gm slab accesses are NONTEMPORAL (don't evict the 640KB weight set from L2)
//  - adj -> 1KB LDS bitmask (adj is exactly {0,1}); w_ih/biases preloaded to LDS
//  - block = 1024 threads (16 waves, 50% occupancy), 1 col-tile-group per wave

#define BB 2048
#define NN 32
#define VV 10
#define HH 256
#define ZZ 64
#define BT 8      // batches per block
#define KC 8      // K chunks: 256/32
#define NT1 48    // 768/16 col tiles (w_hh)
#define NT2 32    // 512/16 col tiles (w_gate||w_map)
#define WHH_ELEMS (NT1 * KC * 64 * 8)             // 196608 ushorts
#define WGM_ELEMS (NT2 * KC * 64 * 8)             // 131072 ushorts
#define GM_BYTE_OFF ((WHH_ELEMS + WGM_ELEMS) * 2) // 655360 B
#define SLAB_ELEMS (BT * NN * HH)                 // 65536 ushorts
#define SLAB_BYTES (SLAB_ELEMS * 2)               // 131072 B

typedef __attribute__((ext_vector_type(8))) short frag8;            // 8 bf16 (4 VGPR)
typedef __attribute__((ext_vector_type(4))) float facc4;            // MFMA accum
typedef __attribute__((ext_vector_type(4))) unsigned short us4;     // nontemporal-safe

__device__ __forceinline__ float bf2f(unsigned short u) {
    unsigned int x = ((unsigned int)u) << 16;
    return __builtin_bit_cast(float, x);
}
__device__ __forceinline__ unsigned short f2bf(float f) {
    unsigned int x = __builtin_bit_cast(unsigned int, f);
    x += 0x7FFFu + ((x >> 16) & 1u);
    return (unsigned short)(x >> 16);
}
__device__ __forceinline__ float sigm(float x) { return 1.0f / (1.0f + __expf(-x)); }
__device__ __forceinline__ float ldv(const float* p, size_t i) { return p[i]; }
__device__ __forceinline__ float ldv(const unsigned short* p, size_t i) { return bf2f(p[i]); }
__device__ __forceinline__ void stv(float* p, size_t i, float v) { p[i] = v; }
__device__ __forceinline__ void stv(unsigned short* p, size_t i, float v) { p[i] = f2bf(v); }
__device__ __forceinline__ us4 ntld4(const unsigned short* p) {
    return __builtin_nontemporal_load((const us4*)p);
}
__device__ __forceinline__ void ntst(unsigned short* p, unsigned short v) {
    __builtin_nontemporal_store(v, p);
}

// flag=1 => buffers are fp32, flag=0 => bf16. Integer-only tests (fast-math safe).
__global__ void detect_dtype(const unsigned short* __restrict__ w, int* flag) {
    __shared__ int zc, bc;
    if (threadIdx.x == 0) { zc = 0; bc = 0; }
    __syncthreads();
    int z = 0, b = 0;
    for (int i = threadIdx.x; i < 2048; i += 256) {
        unsigned short lo = w[2 * i];            // fp32: low mantissa half / bf16: a value
        if (lo == 0) z++;                        // bf16-rounded fp32 storage => all zero
        unsigned e = (lo >> 7) & 0xFFu;          // bf16 exponent field
        if (e >= 0x86u) b++;                     // |x|>=128 or NaN: impossible for N(0,.05) bf16
    }
    atomicAdd(&zc, z); atomicAdd(&bc, b);
    __syncthreads();
    if (threadIdx.x == 0) *flag = (bc > 0 || zc > 512) ? 1 : 0;
}

// Repack w_hh (256x768) and w_gate||w_map (256x512) into bf16 MFMA B-fragment
// order: frag f=jt*KC+kc; elem[(f*64+lane)*8+j] = W[kc*32+(lane>>4)*8+j][jt*16+(lane&15)]
template <typename T>
__global__ void repack_weights(const T* __restrict__ w_hh,
                               const T* __restrict__ w_gate,
                               const T* __restrict__ w_map,
                               unsigned short* __restrict__ whh_p,
                               unsigned short* __restrict__ wgm_p,
                               const int* __restrict__ flag, int want) {
    if (*flag != want) return;
    int t = blockIdx.x * blockDim.x + threadIdx.x;
    int lane = t & 63;
    int frag = t >> 6;                  // 0..639
    int kbase = (lane >> 4) * 8;
    if (frag < NT1 * KC) {
        int jt = frag / KC, kc = frag % KC;
        int col = jt * 16 + (lane & 15);
        unsigned short* dst = whh_p + ((size_t)frag * 64 + lane) * 8;
        #pragma unroll
        for (int j = 0; j < 8; ++j)
            dst[j] = f2bf(ldv(w_hh, (size_t)(kc * 32 + kbase + j) * 768 + col));
    } else if (frag < (NT1 + NT2) * KC) {
        int f2 = frag - NT1 * KC;
        int jt = f2 / KC, kc = f2 % KC;
        int col = jt * 16 + (lane & 15);
        unsigned short* dst = wgm_p + ((size_t)f2 * 64 + lane) * 8;
        #pragma unroll
        for (int j = 0; j < 8; ++j) {
            int k = kc * 32 + kbase + j;
            dst[j] = f2bf((col < HH) ? ldv(w_gate, (size_t)k * HH + col)
                                     : ldv(w_map, (size_t)k * HH + (col - HH)));
        }
    }
}

template <typename T>
__global__ __launch_bounds__(1024, 4) void vae_main(
    const T* __restrict__ adj,
    const int* __restrict__ ntypes,
    const T* __restrict__ w_ih,
    const T* __restrict__ b_ih,
    const T* __restrict__ b_hh,
    const T* __restrict__ b_gate,
    const T* __restrict__ w_mu,
    const T* __restrict__ b_mu,
    const T* __restrict__ w_std,
    const T* __restrict__ b_std,
    const unsigned short* __restrict__ whh_p,
    const unsigned short* __restrict__ wgm_p,
    unsigned short* __restrict__ gm_base,
    T* __restrict__ out,
    int b_start,
    const int* __restrict__ flag, int want)
{
    if (*flag != want) return;

    __shared__ __align__(16) float agg[BT][HH];             // fp32 agg (8 KB)
    __shared__ __align__(16) unsigned short aggbf[16][264]; // MFMA A src (pad +8)
    __shared__ __align__(16) unsigned short hnew[16][264];  // MFMA A src (pad +8)
    __shared__ unsigned int  amask[BT][NN];                 // adj bitmasks (1 KB)
    __shared__ int           ntva[BT][NN];                  // node types (1 KB)
    __shared__ __align__(16) unsigned short wihL[VV * 776]; // w_ih bf16 (15.5 KB)
    __shared__ __align__(16) float bihL[768], bhhL[768], bgL[HH]; // biases (7 KB)

    const int tid  = threadIdx.x;
    const int lane = tid & 63;
    const int w    = tid >> 6;          // wave 0..15
    const int b0   = b_start + blockIdx.x * BT;

    unsigned short* gms = gm_base + (size_t)blockIdx.x * SLAB_ELEMS;  // per-block slab

    const frag8* whh8 = (const frag8*)whh_p;
    const frag8* wgm8 = (const frag8*)wgm_p;

    // ---- one-time preload ----
    for (int i = 8 * 264 + tid; i < 16 * 264; i += 1024) {
        ((unsigned short*)aggbf)[i] = 0;     // zero rows 8..15 (M=16, 8 valid)
        ((unsigned short*)hnew)[i]  = 0;
    }
    if (tid < 256) {                         // adj -> bitmask (adj is exactly {0,1})
        int bi = tid >> 5, vv = tid & 31;
        unsigned m = 0;
        for (int n = 0; n < NN; ++n)
            if (ldv(adj, ((size_t)(b0 + bi) * NN + n) * NN + vv) != 0.0f) m |= (1u << n);
        amask[bi][vv] = m;
    } else if (tid < 512) {
        int idx = tid - 256;
        int bi = idx >> 5, vv = idx & 31;
        ntva[bi][vv] = ntypes[(b0 + bi) * NN + vv];
    }
    for (int i = tid; i < VV * 768; i += 1024) {
        int r = i / 768, c = i - r * 768;
        wihL[r * 776 + c] = f2bf(ldv(w_ih, (size_t)i));
    }
    for (int i = tid; i < 768; i += 1024) { bihL[i] = ldv(b_ih, i); bhhL[i] = ldv(b_hh, i); }
    if (tid < HH) bgL[tid] = ldv(b_gate, tid);
    __syncthreads();

    for (int v = 0; v < NN; ++v) {
        // ---- A: agg[bi][:] = sum over set bits of gm rows (nontemporal loads)
        if (w < BT) {
            const int bi = w;
            const int h4 = lane * 4;
            unsigned m = amask[bi][v];       // wave-uniform
            float a0 = 0.f, a1 = 0.f, a2 = 0.f, a3 = 0.f;
            const unsigned short* rb = gms + (size_t)bi * NN * HH + h4;
            while (m) {
                int n = __builtin_ctz(m); m &= m - 1;
                us4 g = ntld4(rb + (size_t)n * HH);
                a0 += bf2f(g.x); a1 += bf2f(g.y); a2 += bf2f(g.z); a3 += bf2f(g.w);
            }
            *(float4*)&agg[bi][h4] = make_float4(a0, a1, a2, a3);
            ushort4 ab; ab.x = f2bf(a0); ab.y = f2bf(a1); ab.z = f2bf(a2); ab.w = f2bf(a3);
            *(ushort4*)&aggbf[bi][h4] = ab;
        }
        __syncthreads();

        // ---- B: gh = agg @ w_hh (MFMA) fused with GRU elementwise -> hnew
        {
            frag8 afrag[KC];
            #pragma unroll
            for (int kc = 0; kc < KC; ++kc)
                afrag[kc] = *(const frag8*)&aggbf[lane & 15][kc * 32 + (lane >> 4) * 8];

            const int t = w;                             // triplet: cols t, t+16, t+32
            facc4 aR = {0.f, 0.f, 0.f, 0.f};
            facc4 aZ = {0.f, 0.f, 0.f, 0.f};
            facc4 aN = {0.f, 0.f, 0.f, 0.f};
            const frag8* pR = whh8 + (size_t)(t     ) * (KC * 64) + lane;
            const frag8* pZ = whh8 + (size_t)(t + 16) * (KC * 64) + lane;
            const frag8* pN = whh8 + (size_t)(t + 32) * (KC * 64) + lane;
            #pragma unroll
            for (int kc = 0; kc < KC; ++kc) {
                aR = __builtin_amdgcn_mfma_f32_16x16x32_bf16(afrag[kc], pR[kc * 64], aR, 0, 0, 0);
                aZ = __builtin_amdgcn_mfma_f32_16x16x32_bf16(afrag[kc], pZ[kc * 64], aZ, 0, 0, 0);
                aN = __builtin_amdgcn_mfma_f32_16x16x32_bf16(afrag[kc], pN[kc * 64], aN, 0, 0, 0);
            }
            const int col = t * 16 + (lane & 15);
            const int q = lane >> 4;                     // C row = 4q+i, valid q<2
            if (q < 2) {
                const float bir  = bihL[col],       bhr = bhhL[col];
                const float biz  = bihL[col + 256], bhz = bhhL[col + 256];
                const float bin_ = bihL[col + 512], bhn = bhhL[col + 512];
                #pragma unroll
                for (int i = 0; i < 4; ++i) {
                    const int bi = 4 * q + i;
                    const int ty = ntva[bi][v] * 776;
                    const float xr = bf2f(wihL[ty + col]);
                    const float xz = bf2f(wihL[ty + col + 256]);
                    const float xn = bf2f(wihL[ty + col + 512]);
                    const float r = sigm(xr + bir + aR[i] + bhr);
                    const float z = sigm(xz + biz + aZ[i] + bhz);
                    const float n = tanhf(xn + bin_ + r * (aN[i] + bhn));
                    const float h = (1.f - z) * n + z * agg[bi][col];
                    hnew[bi][col] = f2bf(h);
                }
            }
        }
        __syncthreads();

        // ---- D: gm_v = sigmoid(h@w_gate+b_gate) * (h@w_map); nontemporal store
        {
            frag8 hfrag[KC];
            #pragma unroll
            for (int kc = 0; kc < KC; ++kc)
                hfrag[kc] = *(const frag8*)&hnew[lane & 15][kc * 32 + (lane >> 4) * 8];

            const int t = w;                             // gate tile t, map tile t+16
            facc4 aG = {0.f, 0.f, 0.f, 0.f};
            facc4 aM = {0.f, 0.f, 0.f, 0.f};
            const frag8* pG = wgm8 + (size_t)(t     ) * (KC * 64) + lane;
            const frag8* pM = wgm8 + (size_t)(t + 16) * (KC * 64) + lane;
            #pragma unroll
            for (int kc = 0; kc < KC; ++kc) {
                aG = __builtin_amdgcn_mfma_f32_16x16x32_bf16(hfrag[kc], pG[kc * 64], aG, 0, 0, 0);
                aM = __builtin_amdgcn_mfma_f32_16x16x32_bf16(hfrag[kc], pM[kc * 64], aM, 0, 0, 0);
            }
            const int col = t * 16 + (lane & 15);        // 0..255
            const int q = lane >> 4;
            if (q < 2) {
                const float bg = bgL[col];
                #pragma unroll
                for (int i = 0; i < 4; ++i) {
                    const int bi = 4 * q + i;
                    const float gv = sigm(aG[i] + bg) * aM[i];
                    ntst(gms + (size_t)(bi * NN + v) * HH + col, f2bf(gv));
                }
            }
        }
        __syncthreads();   // hnew/gm consumed before next iteration overwrites
    }

    // ---- Epilogue: hg = h_new(v=31) (in hnew LDS); mu/sigma = hg@w_mu/std + b
    {
        const int bi = w >> 1, half = w & 1, z = lane;   // 2 waves per batch
        float am = 0.f, as = 0.f;
        const int h0 = half * 128;
        #pragma unroll 4
        for (int h = h0; h < h0 + 128; ++h) {
            const float hv = bf2f(hnew[bi][h]);          // LDS broadcast
            am += hv * ldv(w_mu, (size_t)h * ZZ + z);
            as += hv * ldv(w_std, (size_t)h * ZZ + z);
        }
        agg[bi][half * 64 + z]       = am;               // agg LDS reused as scratch
        agg[bi][128 + half * 64 + z] = as;
    }
    __syncthreads();
    if (w < BT) {
        const int bi = w, z = lane;
        const float am = agg[bi][z] + agg[bi][64 + z] + ldv(b_mu, z);
        const float as = agg[bi][128 + z] + agg[bi][192 + z] + ldv(b_std, z);
        stv(out, (size_t)(b0 + bi) * ZZ + z, am);
        stv(out, (size_t)BB * ZZ + (size_t)(b0 + bi) * ZZ + z, as);
    }
}

extern "C" void kernel_launch(void* const* d_in, const int* in_sizes, int n_in,
                              void* d_out, int out_size, void* d_ws, size_t ws_size,
                              hipStream_t stream)
{
    unsigned short* whh_p = (unsigned short*)d_ws;
    unsigned short* wgm_p = whh_p + WHH_ELEMS;
    unsigned short* gm_base = wgm_p + WGM_ELEMS;           // byte offset 655360

    // dtype flag lives in the last aligned 4 bytes of ws
    size_t flag_off = (ws_size >= 8) ? ((ws_size - 4) & ~(size_t)3) : 0;
    int* flag = (int*)((char*)d_ws + flag_off);

    // how many blocks' gm slabs fit between repacked weights and the flag
    long long avail = (long long)flag_off - (long long)GM_BYTE_OFF;
    int cb = (int)(avail / SLAB_BYTES);
    if (cb < 1) cb = 1;                                    // degenerate ws: best effort
    if (cb > BB / BT) cb = BB / BT;

    detect_dtype<<<dim3(1), 256, 0, stream>>>((const unsigned short*)d_in[2], flag);

    repack_weights<float><<<dim3(160), 256, 0, stream>>>(
        (const float*)d_in[3], (const float*)d_in[6], (const float*)d_in[8],
        whh_p, wgm_p, flag, 1);
    repack_weights<unsigned short><<<dim3(160), 256, 0, stream>>>(
        (const unsigned short*)d_in[3], (const unsigned short*)d_in[6],
        (const unsigned short*)d_in[8], whh_p, wgm_p, flag, 0);

    const int nblk = BB / BT;                              // 256
    for (int blk0 = 0; blk0 < nblk; blk0 += cb) {
        int g = nblk - blk0; if (g > cb) g = cb;
        vae_main<float><<<dim3(g), 1024, 0, stream>>>(
            (const float*)d_in[0], (const int*)d_in[1], (const float*)d_in[2],
            (const float*)d_in[4], (const float*)d_in[5], (const float*)d_in[7],
            (const float*)d_in[9], (const float*)d_in[10], (const float*)d_in[11],
            (const float*)d_in[12],
            whh_p, wgm_p, gm_base, (float*)d_out, blk0 * BT, flag, 1);
        vae_main<unsigned short><<<dim3(g), 1024, 0, stream>>>(
            (const unsigned short*)d_in[0], (const int*)d_in[1],
            (const unsigned short*)d_in[2], (const unsigned short*)d_in[4],
            (const unsigned short*)d_in[5], (const unsigned short*)d_in[7],
            (const unsigned short*)d_in[9], (const unsigned short*)d_in[10],
            (const unsigned short*)d_in[11], (const unsigned short*)d_in[12],
            whh_p, wgm_p, gm_base, (unsigned short*)d_out, blk0 * BT, flag, 0);
    }
}

// Round 5
// 558.999 us; speedup vs baseline: 1.3853x; 1.0384x over previous
//
#include <hip/hip_runtime.h>

// LogicVAE: graph-GRU VAE encoder. B=2048,N=32,V=10,H=256,Z=64.
// gm[b,n] = sigmoid(h@w_gate+b_gate)*(h@w_map) is a pure function of the FINAL
// hidden[b,n] (adj strictly upper-tri), so it's computed once per node.
// R5 vs R4 (580us, WRITE 126MB = 4x amplification from 2B nt scatter stores):
//  - phase D stages gm row in LDS; 4-wave team writes FULL 512B lines (nt b128)
//    during phase A of the next step; phase A reads row v-1 from LDS directly
//  - phase-D gate tile pinned in VGPRs across all 32 steps (~100 VGPR < 128 cap)

#define BB 2048
#define NN 32
#define VV 10
#define HH 256
#define ZZ 64
#define BT 8      // batches per block
#define KC 8      // K chunks: 256/32
#define NT1 48    // 768/16 col tiles (w_hh)
#define NT2 32    // 512/16 col tiles (w_gate||w_map)
#define WHH_ELEMS (NT1 * KC * 64 * 8)             // 196608 ushorts
#define WGM_ELEMS (NT2 * KC * 64 * 8)             // 131072 ushorts
#define GM_BYTE_OFF ((WHH_ELEMS + WGM_ELEMS) * 2) // 655360 B
#define SLAB_ELEMS (BT * NN * HH)                 // 65536 ushorts
#define SLAB_BYTES (SLAB_ELEMS * 2)               // 131072 B

typedef __attribute__((ext_vector_type(8))) short frag8;            // 8 bf16 (4 VGPR)
typedef __attribute__((ext_vector_type(4))) float facc4;            // MFMA accum
typedef __attribute__((ext_vector_type(4))) unsigned short us4;     // nontemporal-safe
typedef __attribute__((ext_vector_type(8))) unsigned short us8;     // 16B nt store

__device__ __forceinline__ float bf2f(unsigned short u) {
    unsigned int x = ((unsigned int)u) << 16;
    return __builtin_bit_cast(float, x);
}
__device__ __forceinline__ unsigned short f2bf(float f) {
    unsigned int x = __builtin_bit_cast(unsigned int, f);
    x += 0x7FFFu + ((x >> 16) & 1u);
    return (unsigned short)(x >> 16);
}
__device__ __forceinline__ float sigm(float x) { return 1.0f / (1.0f + __expf(-x)); }
__device__ __forceinline__ float ldv(const float* p, size_t i) { return p[i]; }
__device__ __forceinline__ float ldv(const unsigned short* p, size_t i) { return bf2f(p[i]); }
__device__ __forceinline__ void stv(float* p, size_t i, float v) { p[i] = v; }
__device__ __forceinline__ void stv(unsigned short* p, size_t i, float v) { p[i] = f2bf(v); }
__device__ __forceinline__ us4 ntld4(const unsigned short* p) {
    return __builtin_nontemporal_load((const us4*)p);
}
__device__ __forceinline__ void ntst16(unsigned short* p, us8 v) {
    __builtin_nontemporal_store(v, (us8*)p);
}

// flag=1 => buffers are fp32, flag=0 => bf16. Integer-only tests (fast-math safe).
__global__ void detect_dtype(const unsigned short* __restrict__ w, int* flag) {
    __shared__ int zc, bc;
    if (threadIdx.x == 0) { zc = 0; bc = 0; }
    __syncthreads();
    int z = 0, b = 0;
    for (int i = threadIdx.x; i < 2048; i += 256) {
        unsigned short lo = w[2 * i];            // fp32: low mantissa half / bf16: a value
        if (lo == 0) z++;                        // bf16-rounded fp32 storage => all zero
        unsigned e = (lo >> 7) & 0xFFu;          // bf16 exponent field
        if (e >= 0x86u) b++;                     // |x|>=128 or NaN: impossible for N(0,.05) bf16
    }
    atomicAdd(&zc, z); atomicAdd(&bc, b);
    __syncthreads();
    if (threadIdx.x == 0) *flag = (bc > 0 || zc > 512) ? 1 : 0;
}

// Repack w_hh (256x768) and w_gate||w_map (256x512) into bf16 MFMA B-fragment
// order: frag f=jt*KC+kc; elem[(f*64+lane)*8+j] = W[kc*32+(lane>>4)*8+j][jt*16+(lane&15)]
template <typename T>
__global__ void repack_weights(const T* __restrict__ w_hh,
                               const T* __restrict__ w_gate,
                               const T* __restrict__ w_map,
                               unsigned short* __restrict__ whh_p,
                               unsigned short* __restrict__ wgm_p,
                               const int* __restrict__ flag, int want) {
    if (*flag != want) return;
    int t = blockIdx.x * blockDim.x + threadIdx.x;
    int lane = t & 63;
    int frag = t >> 6;                  // 0..639
    int kbase = (lane >> 4) * 8;
    if (frag < NT1 * KC) {
        int jt = frag / KC, kc = frag % KC;
        int col = jt * 16 + (lane & 15);
        unsigned short* dst = whh_p + ((size_t)frag * 64 + lane) * 8;
        #pragma unroll
        for (int j = 0; j < 8; ++j)
            dst[j] = f2bf(ldv(w_hh, (size_t)(kc * 32 + kbase + j) * 768 + col));
    } else if (frag < (NT1 + NT2) * KC) {
        int f2 = frag - NT1 * KC;
        int jt = f2 / KC, kc = f2 % KC;
        int col = jt * 16 + (lane & 15);
        unsigned short* dst = wgm_p + ((size_t)f2 * 64 + lane) * 8;
        #pragma unroll
        for (int j = 0; j < 8; ++j) {
            int k = kc * 32 + kbase + j;
            dst[j] = f2bf((col < HH) ? ldv(w_gate, (size_t)k * HH + col)
                                     : ldv(w_map, (size_t)k * HH + (col - HH)));
        }
    }
}

template <typename T>
__global__ __launch_bounds__(1024, 4) void vae_main(
    const T* __restrict__ adj,
    const int* __restrict__ ntypes,
    const T* __restrict__ w_ih,
    const T* __restrict__ b_ih,
    const T* __restrict__ b_hh,
    const T* __restrict__ b_gate,
    const T* __restrict__ w_mu,
    const T* __restrict__ b_mu,
    const T* __restrict__ w_std,
    const T* __restrict__ b_std,
    const unsigned short* __restrict__ whh_p,
    const unsigned short* __restrict__ wgm_p,
    unsigned short* __restrict__ gm_base,
    T* __restrict__ out,
    int b_start,
    const int* __restrict__ flag, int want)
{
    if (*flag != want) return;

    __shared__ __align__(16) float agg[BT][HH];             // fp32 agg (8 KB)
    __shared__ __align__(16) unsigned short aggbf[16][264]; // MFMA A src (pad +8)
    __shared__ __align__(16) unsigned short hnew[16][264];  // MFMA A src (pad +8)
    __shared__ __align__(16) unsigned short gmrow[BT][HH];  // step's gm row (4 KB)
    __shared__ unsigned int  amask[BT][NN];                 // adj bitmasks (1 KB)
    __shared__ int           ntva[BT][NN];                  // node types (1 KB)
    __shared__ __align__(16) unsigned short wihL[VV * 776]; // w_ih bf16 (15.5 KB)
    __shared__ __align__(16) float bihL[768], bhhL[768], bgL[HH]; // biases (7 KB)

    const int tid  = threadIdx.x;
    const int lane = tid & 63;
    const int w    = tid >> 6;          // wave 0..15
    const int b0   = b_start + blockIdx.x * BT;

    unsigned short* gms = gm_base + (size_t)blockIdx.x * SLAB_ELEMS;  // per-block slab

    const frag8* whh8 = (const frag8*)whh_p;
    const frag8* wgm8 = (const frag8*)wgm_p;

    // ---- one-time preload ----
    for (int i = 8 * 264 + tid; i < 16 * 264; i += 1024) {
        ((unsigned short*)aggbf)[i] = 0;     // zero rows 8..15 (M=16, 8 valid)
        ((unsigned short*)hnew)[i]  = 0;
    }
    if (tid < 256) {                         // adj -> bitmask (adj is exactly {0,1})
        int bi = tid >> 5, vv = tid & 31;
        unsigned m = 0;
        for (int n = 0; n < NN; ++n)
            if (ldv(adj, ((size_t)(b0 + bi) * NN + n) * NN + vv) != 0.0f) m |= (1u << n);
        amask[bi][vv] = m;
    } else if (tid < 512) {
        int idx = tid - 256;
        int bi = idx >> 5, vv = idx & 31;
        ntva[bi][vv] = ntypes[(b0 + bi) * NN + vv];
    }
    for (int i = tid; i < VV * 768; i += 1024) {
        int r = i / 768, c = i - r * 768;
        wihL[r * 776 + c] = f2bf(ldv(w_ih, (size_t)i));
    }
    for (int i = tid; i < 768; i += 1024) { bihL[i] = ldv(b_ih, i); bhhL[i] = ldv(b_hh, i); }
    if (tid < HH) bgL[tid] = ldv(b_gate, tid);

    // ---- pin phase-D gate tile in VGPRs for all 32 steps (~32 regs) ----
    frag8 wG[KC];
    {
        const frag8* pG = wgm8 + (size_t)w * (KC * 64) + lane;
        #pragma unroll
        for (int kc = 0; kc < KC; ++kc) wG[kc] = pG[kc * 64];
    }
    __syncthreads();

    for (int v = 0; v < NN; ++v) {
        // ---- A (waves 0..7): agg over neighbor gm rows; row v-1 comes from LDS.
        //      (waves 8..11): write out previous step's gm row, full 512B lines.
        if (w < BT) {
            const int bi = w;
            const int h4 = lane * 4;
            unsigned m0 = amask[bi][v];      // wave-uniform
            unsigned m  = (v > 0) ? (m0 & ~(1u << (v - 1))) : m0;
            float a0 = 0.f, a1 = 0.f, a2 = 0.f, a3 = 0.f;
            const unsigned short* rb = gms + (size_t)bi * NN * HH + h4;
            while (m) {
                int n = __builtin_ctz(m); m &= m - 1;
                us4 g = ntld4(rb + (size_t)n * HH);   // >=2 steps old -> global
                a0 += bf2f(g.x); a1 += bf2f(g.y); a2 += bf2f(g.z); a3 += bf2f(g.w);
            }
            if (v > 0 && ((m0 >> (v - 1)) & 1u)) {    // newest row: still in LDS
                const unsigned short* gr = &gmrow[bi][h4];
                a0 += bf2f(gr[0]); a1 += bf2f(gr[1]);
                a2 += bf2f(gr[2]); a3 += bf2f(gr[3]);
            }
            *(float4*)&agg[bi][h4] = make_float4(a0, a1, a2, a3);
            ushort4 ab; ab.x = f2bf(a0); ab.y = f2bf(a1); ab.z = f2bf(a2); ab.w = f2bf(a3);
            *(ushort4*)&aggbf[bi][h4] = ab;
        } else if (w < 12 && v > 0) {
            const int bi = (w - 8) * 2 + (lane >> 5); // 4 waves cover 8 rows
            const int c8 = (lane & 31) * 8;           // 16B per lane, 512B per row
            us8 val = *(const us8*)&gmrow[bi][c8];
            ntst16(gms + ((size_t)bi * NN + (v - 1)) * HH + c8, val);
        }
        __syncthreads();

        // ---- B: gh = agg @ w_hh (MFMA) fused with GRU elementwise -> hnew
        {
            frag8 afrag[KC];
            #pragma unroll
            for (int kc = 0; kc < KC; ++kc)
                afrag[kc] = *(const frag8*)&aggbf[lane & 15][kc * 32 + (lane >> 4) * 8];

            const int t = w;                             // triplet: cols t, t+16, t+32
            facc4 aR = {0.f, 0.f, 0.f, 0.f};
            facc4 aZ = {0.f, 0.f, 0.f, 0.f};
            facc4 aN = {0.f, 0.f, 0.f, 0.f};
            const frag8* pR = whh8 + (size_t)(t     ) * (KC * 64) + lane;
            const frag8* pZ = whh8 + (size_t)(t + 16) * (KC * 64) + lane;
            const frag8* pN = whh8 + (size_t)(t + 32) * (KC * 64) + lane;
            #pragma unroll
            for (int kc = 0; kc < KC; ++kc) {
                aR = __builtin_amdgcn_mfma_f32_16x16x32_bf16(afrag[kc], pR[kc * 64], aR, 0, 0, 0);
                aZ = __builtin_amdgcn_mfma_f32_16x16x32_bf16(afrag[kc], pZ[kc * 64], aZ, 0, 0, 0);
                aN = __builtin_amdgcn_mfma_f32_16x16x32_bf16(afrag[kc], pN[kc * 64], aN, 0, 0, 0);
            }
            const int col = t * 16 + (lane & 15);
            const int q = lane >> 4;                     // C row = 4q+i, valid q<2
            if (q < 2) {
                const float bir  = bihL[col],       bhr = bhhL[col];
                const float biz  = bihL[col + 256], bhz = bhhL[col + 256];
                const float bin_ = bihL[col + 512], bhn = bhhL[col + 512];
                #pragma unroll
                for (int i = 0; i < 4; ++i) {
                    const int bi = 4 * q + i;
                    const int ty = ntva[bi][v] * 776;
                    const float xr = bf2f(wihL[ty + col]);
                    const float xz = bf2f(wihL[ty + col + 256]);
                    const float xn = bf2f(wihL[ty + col + 512]);
                    const float r = sigm(xr + bir + aR[i] + bhr);
                    const float z = sigm(xz + biz + aZ[i] + bhz);
                    const float n = tanhf(xn + bin_ + r * (aN[i] + bhn));
                    const float h = (1.f - z) * n + z * agg[bi][col];
                    hnew[bi][col] = f2bf(h);
                }
            }
        }
        __syncthreads();

        // ---- D: gm_v = sigmoid(h@w_gate+b_gate) * (h@w_map) -> gmrow (LDS)
        {
            frag8 hfrag[KC];
            #pragma unroll
            for (int kc = 0; kc < KC; ++kc)
                hfrag[kc] = *(const frag8*)&hnew[lane & 15][kc * 32 + (lane >> 4) * 8];

            const int t = w;                             // gate tile t (pinned), map t+16
            facc4 aG = {0.f, 0.f, 0.f, 0.f};
            facc4 aM = {0.f, 0.f, 0.f, 0.f};
            const frag8* pM = wgm8 + (size_t)(t + 16) * (KC * 64) + lane;
            #pragma unroll
            for (int kc = 0; kc < KC; ++kc) {
                aG = __builtin_amdgcn_mfma_f32_16x16x32_bf16(hfrag[kc], wG[kc], aG, 0, 0, 0);
                aM = __builtin_amdgcn_mfma_f32_16x16x32_bf16(hfrag[kc], pM[kc * 64], aM, 0, 0, 0);
            }
            const int col = t * 16 + (lane & 15);        // 0..255
            const int q = lane >> 4;
            if (q < 2) {
                const float bg = bgL[col];
                #pragma unroll
                for (int i = 0; i < 4; ++i) {
                    const int bi = 4 * q + i;
                    gmrow[bi][col] = f2bf(sigm(aG[i] + bg) * aM[i]);
                }
            }
        }
        __syncthreads();   // gmrow/hnew ready for next step's A / epilogue
    }

    // ---- Epilogue: hg = h_new(v=31) (in hnew LDS); mu/sigma = hg@w_mu/std + b
    {
        const int bi = w >> 1, half = w & 1, z = lane;   // 2 waves per batch
        float am = 0.f, as = 0.f;
        const int h0 = half * 128;
        #pragma unroll 4
        for (int h = h0; h < h0 + 128; ++h) {
            const float hv = bf2f(hnew[bi][h]);          // LDS broadcast
            am += hv * ldv(w_mu, (size_t)h * ZZ + z);
            as += hv * ldv(w_std, (size_t)h * ZZ + z);
        }
        agg[bi][half * 64 + z]       = am;               // agg LDS reused as scratch
        agg[bi][128 + half * 64 + z] = as;
    }
    __syncthreads();
    if (w < BT) {
        const int bi = w, z = lane;
        const float am = agg[bi][z] + agg[bi][64 + z] + ldv(b_mu, z);
        const float as = agg[bi][128 + z] + agg[bi][192 + z] + ldv(b_std, z);
        stv(out, (size_t)(b0 + bi) * ZZ + z, am);
        stv(out, (size_t)BB * ZZ + (size_t)(b0 + bi) * ZZ + z, as);
    }
}

extern "C" void kernel_launch(void* const* d_in, const int* in_sizes, int n_in,
                              void* d_out, int out_size, void* d_ws, size_t ws_size,
                              hipStream_t stream)
{
    unsigned short* whh_p = (unsigned short*)d_ws;
    unsigned short* wgm_p = whh_p + WHH_ELEMS;
    unsigned short* gm_base = wgm_p + WGM_ELEMS;           // byte offset 655360

    // dtype flag lives in the last aligned 4 bytes of ws
    size_t flag_off = (ws_size >= 8) ? ((ws_size - 4) & ~(size_t)3) : 0;
    int* flag = (int*)((char*)d_ws + flag_off);

    // how many blocks' gm slabs fit between repacked weights and the flag
    long long avail = (long long)flag_off - (long long)GM_BYTE_OFF;
    int cb = (int)(avail / SLAB_BYTES);
    if (cb < 1) cb = 1;                                    // degenerate ws: best effort
    if (cb > BB / BT) cb = BB / BT;

    detect_dtype<<<dim3(1), 256, 0, stream>>>((const unsigned short*)d_in[2], flag);

    repack_weights<float><<<dim3(160), 256, 0, stream>>>(
        (const float*)d_in[3], (const float*)d_in[6], (const float*)d_in[8],
        whh_p, wgm_p, flag, 1);
    repack_weights<unsigned short><<<dim3(160), 256, 0, stream>>>(
        (const unsigned short*)d_in[3], (const unsigned short*)d_in[6],
        (const unsigned short*)d_in[8], whh_p, wgm_p, flag, 0);

    const int nblk = BB / BT;                              // 256
    for (int blk0 = 0; blk0 < nblk; blk0 += cb) {
        int g = nblk - blk0; if (g > cb) g = cb;
        vae_main<float><<<dim3(g), 1024, 0, stream>>>(
            (const float*)d_in[0], (const int*)d_in[1], (const float*)d_in[2],
            (const float*)d_in[4], (const float*)d_in[5], (const float*)d_in[7],
            (const float*)d_in[9], (const float*)d_in[10], (const float*)d_in[11],
            (const float*)d_in[12],
            whh_p, wgm_p, gm_base, (float*)d_out, blk0 * BT, flag, 1);
        vae_main<unsigned short><<<dim3(g), 1024, 0, stream>>>(
            (const unsigned short*)d_in[0], (const int*)d_in[1],
            (const unsigned short*)d_in[2], (const unsigned short*)d_in[4],
            (const unsigned short*)d_in[5], (const unsigned short*)d_in[7],
            (const unsigned short*)d_in[9], (const unsigned short*)d_in[10],
            (const unsigned short*)d_in[11], (const unsigned short*)d_in[12],
            whh_p, wgm_p, gm_base, (unsigned short*)d_out, blk0 * BT, flag, 0);
    }
}